// Round 1
// baseline (6176.691 us; speedup 1.0000x reference)
//
#include <hip/hip_runtime.h>

#define FDIM 128
#define NREL 8

// ---------------- utility kernels ----------------

__global__ void zero_f4(float4* __restrict__ p, long n4) {
  long i = (long)blockIdx.x * blockDim.x + threadIdx.x;
  long s = (long)gridDim.x * blockDim.x;
  float4 z = make_float4(0.f, 0.f, 0.f, 0.f);
  for (; i < n4; i += s) p[i] = z;
}

__global__ void relu_f4(float4* __restrict__ p, long n4) {
  long i = (long)blockIdx.x * blockDim.x + threadIdx.x;
  long s = (long)gridDim.x * blockDim.x;
  for (; i < n4; i += s) {
    float4 v = p[i];
    v.x = fmaxf(v.x, 0.f); v.y = fmaxf(v.y, 0.f);
    v.z = fmaxf(v.z, 0.f); v.w = fmaxf(v.w, 0.f);
    p[i] = v;
  }
}

// count edges per (relation, dst): cnt[r*N + v] += 1
__global__ void count_k(const int* __restrict__ dst, const int* __restrict__ et,
                        int E, float* __restrict__ cnt, int N) {
  int e = blockIdx.x * 256 + threadIdx.x;
  if (e < E) atomicAdd(&cnt[(long)et[e] * N + dst[e]], 1.0f);
}

// in-place: c = 1 / max(c, 1)
__global__ void invert_k(float* __restrict__ c, long n) {
  long i = (long)blockIdx.x * blockDim.x + threadIdx.x;
  long s = (long)gridDim.x * blockDim.x;
  for (; i < n; i += s) c[i] = 1.0f / fmaxf(c[i], 1.0f);
}

// scatter-add x[src] into pre[dst] for edges of relation `rel`.
// 32 lanes per edge, one float4 per lane (128 floats/row).
__global__ void scatter_k(const float* __restrict__ x, const int* __restrict__ src,
                          const int* __restrict__ dst, const int* __restrict__ et,
                          int E, int rel, float* __restrict__ pre) {
  int eg = blockIdx.x * (256 / 32) + (threadIdx.x >> 5);
  if (eg >= E) return;
  if (et[eg] != rel) return;
  int lane = threadIdx.x & 31;
  const float4 v = ((const float4*)(x + (long)src[eg] * FDIM))[lane];
  float* o = pre + (long)dst[eg] * FDIM + lane * 4;
  atomicAdd(o + 0, v.x);
  atomicAdd(o + 1, v.y);
  atomicAdd(o + 2, v.z);
  atomicAdd(o + 3, v.w);
}

// ---------------- skinny GEMM: C[N,128] (+)= (A[N,128] * scale) @ B[128,128] ----------------
// MODE 0: C = A@B + bias          (root transform)
// MODE 1: C += (A * scale[row]) @ B   (per-relation mean-aggregated transform)
// Tile: 128 rows/block, 256 threads; B and A tile staged in LDS (64KB + 64KB).
template <int MODE>
__global__ __launch_bounds__(256, 1) void mm128(const float* __restrict__ A,
                                                const float* __restrict__ B,
                                                const float* __restrict__ bias,
                                                const float* __restrict__ scale,
                                                float* __restrict__ C, int N) {
  __shared__ float Bs[FDIM * FDIM];   // 64 KB
  __shared__ float As[128 * FDIM];    // 64 KB
  const int tid = threadIdx.x;

  // stage B (16384 floats = 4096 float4, 16 per thread), coalesced
  {
    const float4* Bv = (const float4*)B;
    float4* Bsv = (float4*)Bs;
#pragma unroll
    for (int i = 0; i < 16; ++i) Bsv[tid + 256 * i] = Bv[tid + 256 * i];
  }

  const int row0 = blockIdx.x * 128;
  // stage A tile (128 rows x 128 cols = 4096 float4), scale rows if MODE==1
  {
    float4* Asv = (float4*)As;
    for (int i = tid; i < 128 * 32; i += 256) {
      int r = i >> 5;      // row within tile
      int c = i & 31;      // float4 col
      int grow = row0 + r;
      float4 v = make_float4(0.f, 0.f, 0.f, 0.f);
      if (grow < N) {
        v = ((const float4*)(A + (long)grow * FDIM))[c];
        if (MODE == 1) {
          float s = scale[grow];
          v.x *= s; v.y *= s; v.z *= s; v.w *= s;
        }
      }
      Asv[i] = v;
    }
  }
  __syncthreads();

  const int cg = tid & 31;   // col group: cols cg*4 .. cg*4+3
  const int rg = tid >> 5;   // row group: rows rg*16 .. rg*16+15

  float acc[16][4];
  if (MODE == 0) {
    float4 bv = ((const float4*)bias)[cg];
#pragma unroll
    for (int i = 0; i < 16; ++i) {
      acc[i][0] = bv.x; acc[i][1] = bv.y; acc[i][2] = bv.z; acc[i][3] = bv.w;
    }
  } else {
#pragma unroll
    for (int i = 0; i < 16; ++i) {
      acc[i][0] = 0.f; acc[i][1] = 0.f; acc[i][2] = 0.f; acc[i][3] = 0.f;
    }
  }

  for (int k = 0; k < FDIM; k += 4) {
    float4 b0 = *(const float4*)&Bs[(k + 0) * FDIM + cg * 4];
    float4 b1 = *(const float4*)&Bs[(k + 1) * FDIM + cg * 4];
    float4 b2 = *(const float4*)&Bs[(k + 2) * FDIM + cg * 4];
    float4 b3 = *(const float4*)&Bs[(k + 3) * FDIM + cg * 4];
#pragma unroll
    for (int i = 0; i < 16; ++i) {
      float4 a = *(const float4*)&As[(rg * 16 + i) * FDIM + k];
      acc[i][0] = fmaf(a.w, b3.x, fmaf(a.z, b2.x, fmaf(a.y, b1.x, fmaf(a.x, b0.x, acc[i][0]))));
      acc[i][1] = fmaf(a.w, b3.y, fmaf(a.z, b2.y, fmaf(a.y, b1.y, fmaf(a.x, b0.y, acc[i][1]))));
      acc[i][2] = fmaf(a.w, b3.z, fmaf(a.z, b2.z, fmaf(a.y, b1.z, fmaf(a.x, b0.z, acc[i][2]))));
      acc[i][3] = fmaf(a.w, b3.w, fmaf(a.z, b2.w, fmaf(a.y, b1.w, fmaf(a.x, b0.w, acc[i][3]))));
    }
  }

#pragma unroll
  for (int i = 0; i < 16; ++i) {
    int grow = row0 + rg * 16 + i;
    if (grow < N) {
      float4* cp = (float4*)(C + (long)grow * FDIM) + cg;
      if (MODE == 1) {
        float4 old = *cp;
        old.x += acc[i][0]; old.y += acc[i][1]; old.z += acc[i][2]; old.w += acc[i][3];
        *cp = old;
      } else {
        *cp = make_float4(acc[i][0], acc[i][1], acc[i][2], acc[i][3]);
      }
    }
  }
}

// ---------------- host launch ----------------

extern "C" void kernel_launch(void* const* d_in, const int* in_sizes, int n_in,
                              void* d_out, int out_size, void* d_ws, size_t ws_size,
                              hipStream_t stream) {
  const float* x = (const float*)d_in[0];
  const int* ei = (const int*)d_in[1];
  const int* et = (const int*)d_in[2];
  const float* W[3]    = {(const float*)d_in[3], (const float*)d_in[6], (const float*)d_in[9]};
  const float* root[3] = {(const float*)d_in[4], (const float*)d_in[7], (const float*)d_in[10]};
  const float* bias[3] = {(const float*)d_in[5], (const float*)d_in[8], (const float*)d_in[11]};

  const int N = in_sizes[0] / FDIM;
  const int E = in_sizes[1] / 2;
  const int* src = ei;
  const int* dst = ei + E;

  float* ws  = (float*)d_ws;
  float* inv = ws;                               // [NREL * N]   inverse counts
  float* pre = inv + (size_t)NREL * N;           // [N * FDIM]   per-relation aggregate
  float* h1  = pre + (size_t)N * FDIM;           // [N * FDIM]
  float* h2  = h1 + (size_t)N * FDIM;            // [N * FDIM]
  float* out = (float*)d_out;

  // ---- per-(relation,dst) mean normalizers (edges are layer-invariant) ----
  zero_f4<<<1024, 256, 0, stream>>>((float4*)inv, (long)NREL * N / 4);
  count_k<<<(E + 255) / 256, 256, 0, stream>>>(dst, et, E, inv, N);
  invert_k<<<1024, 256, 0, stream>>>(inv, (long)NREL * N);

  const int mm_grid = (N + 127) / 128;
  const float* in_p = x;
  float* outs[3] = {h1, h2, out};

  for (int L = 0; L < 3; ++L) {
    float* o = outs[L];
    // root/self transform: o = in @ root + bias
    mm128<0><<<mm_grid, 256, 0, stream>>>(in_p, root[L], bias[L], nullptr, o, N);
    for (int r = 0; r < NREL; ++r) {
      zero_f4<<<2048, 256, 0, stream>>>((float4*)pre, (long)N * FDIM / 4);
      scatter_k<<<(E + 7) / 8, 256, 0, stream>>>(in_p, src, dst, et, E, r, pre);
      // o += (pre * inv_cnt_r) @ W[L][r]
      mm128<1><<<mm_grid, 256, 0, stream>>>(pre, W[L] + (size_t)r * FDIM * FDIM,
                                            nullptr, inv + (size_t)r * N, o, N);
    }
    relu_f4<<<2048, 256, 0, stream>>>((float4*)o, (long)N * FDIM / 4);
    in_p = o;
  }
}

// Round 2
// 837.739 us; speedup vs baseline: 7.3730x; 7.3730x over previous
//
#include <hip/hip_runtime.h>

#define FDIM 128
#define NREL 8
#define SCHUNK 4096

typedef __attribute__((ext_vector_type(8))) short bf16x8;
typedef __attribute__((ext_vector_type(8))) unsigned short u16x8;
typedef __attribute__((ext_vector_type(4))) float f32x4;

__device__ __forceinline__ unsigned short f2bf(float f) {
  unsigned int u = __float_as_uint(f);
  u += 0x7fffu + ((u >> 16) & 1u);   // round-to-nearest-even
  return (unsigned short)(u >> 16);
}

// ---------------- prep kernels (run once; edges are layer-invariant) ----------------

__global__ void zero_u32(unsigned int* __restrict__ p, long n) {
  long i = (long)blockIdx.x * blockDim.x + threadIdx.x;
  long s = (long)gridDim.x * blockDim.x;
  for (; i < n; i += s) p[i] = 0u;
}

__global__ void hist_k(const int* __restrict__ dst, const int* __restrict__ et,
                       int E, int* __restrict__ cnt, int N) {
  int e = blockIdx.x * 256 + threadIdx.x;
  if (e < E) atomicAdd(&cnt[et[e] * N + dst[e]], 1);
}

__global__ void scan_partial(const int* __restrict__ cnt, int n, int* __restrict__ sums) {
  __shared__ int red[256];
  int base = blockIdx.x * SCHUNK;
  int s = 0;
  for (int i = threadIdx.x; i < SCHUNK; i += 256) {
    int j = base + i;
    s += (j < n) ? cnt[j] : 0;
  }
  red[threadIdx.x] = s;
  __syncthreads();
  for (int o = 128; o > 0; o >>= 1) {
    if (threadIdx.x < o) red[threadIdx.x] += red[threadIdx.x + o];
    __syncthreads();
  }
  if (threadIdx.x == 0) sums[blockIdx.x] = red[0];
}

__global__ void scan_sums(int* __restrict__ sums, int nb) {
  __shared__ int tmp[256];
  int t = threadIdx.x;
  int v = (t < nb) ? sums[t] : 0;
  tmp[t] = v;
  __syncthreads();
  for (int o = 1; o < 256; o <<= 1) {
    int u = (t >= o) ? tmp[t - o] : 0;
    __syncthreads();
    tmp[t] += u;
    __syncthreads();
  }
  if (t < nb) sums[t] = tmp[t] - v;  // exclusive
}

__global__ void scan_final(const int* __restrict__ cnt, int n,
                           const int* __restrict__ sums, int* __restrict__ off) {
  __shared__ int red[256];
  int t = threadIdx.x;
  int base = blockIdx.x * SCHUNK;
  int loc[16];
  int s = 0;
#pragma unroll
  for (int i = 0; i < 16; ++i) {
    int j = base + t * 16 + i;
    int v = (j < n) ? cnt[j] : 0;
    loc[i] = s;
    s += v;
  }
  red[t] = s;
  __syncthreads();
  int mine = s;
  for (int o = 1; o < 256; o <<= 1) {
    int u = (t >= o) ? red[t - o] : 0;
    __syncthreads();
    red[t] += u;
    __syncthreads();
  }
  int tp = red[t] - mine;
  int bb = sums[blockIdx.x];
#pragma unroll
  for (int i = 0; i < 16; ++i) {
    int j = base + t * 16 + i;
    if (j < n) off[j] = bb + tp + loc[i];
  }
}

__global__ void sort_k(const int* __restrict__ src, const int* __restrict__ dst,
                       const int* __restrict__ et, int E, int* __restrict__ cur,
                       int* __restrict__ ss, int N) {
  int e = blockIdx.x * 256 + threadIdx.x;
  if (e < E) {
    int key = et[e] * N + dst[e];
    int p = atomicAdd(&cur[key], 1);
    ss[p] = src[e];
  }
}

// transpose {root, W0..W7} per layer into bf16 [j][k]; 27 blocks
__global__ void wtrans_k(const float* __restrict__ r1, const float* __restrict__ w1,
                         const float* __restrict__ r2, const float* __restrict__ w2,
                         const float* __restrict__ r3, const float* __restrict__ w3,
                         unsigned short* __restrict__ Wt) {
  int b = blockIdx.x;
  int L = b / 9, s = b % 9;
  const float* root = (L == 0) ? r1 : (L == 1) ? r2 : r3;
  const float* W = (L == 0) ? w1 : (L == 1) ? w2 : w3;
  const float* src = (s == 0) ? root : W + (size_t)(s - 1) * FDIM * FDIM;
  unsigned short* out = Wt + (size_t)b * FDIM * FDIM;
  for (int i = threadIdx.x; i < FDIM * FDIM; i += 256) {
    int j = i >> 7, k = i & 127;
    out[i] = f2bf(src[k * FDIM + j]);
  }
}

// ---------------- per-layer: segment mean (sorted CSR, no atomics) ----------------
// one 32-lane group per key; writes mean row (bf16), zeros for empty segments.
__global__ void seg_mean_k(const float* __restrict__ x, const int* __restrict__ ss,
                           const int* __restrict__ off, int key0, int nkeys,
                           unsigned short* __restrict__ pre) {
  int g = blockIdx.x * 8 + (threadIdx.x >> 5);
  if (g >= nkeys) return;
  int lane = threadIdx.x & 31;
  int s = off[key0 + g], e = off[key0 + g + 1];
  float4 a = make_float4(0.f, 0.f, 0.f, 0.f);
  for (int i = s; i < e; ++i) {
    const float4 v = ((const float4*)(x + (size_t)ss[i] * FDIM))[lane];
    a.x += v.x; a.y += v.y; a.z += v.z; a.w += v.w;
  }
  float sc = (e > s) ? 1.0f / (float)(e - s) : 0.f;
  ushort4 o;
  o.x = f2bf(a.x * sc); o.y = f2bf(a.y * sc);
  o.z = f2bf(a.z * sc); o.w = f2bf(a.w * sc);
  ((ushort4*)(pre + (size_t)g * FDIM))[lane] = o;
}

// ---------------- fused layer GEMM: C[N,128] = [bias +] sum_s A_s @ Wt_s [, relu] ----
// A_0 = fp32 input (root) when A0 != null; A_{1..} = bf16 mean-aggregates.
// MFMA 16x16x32 bf16, fp32 accum. LDS tiles XOR-swizzled in 16B units.
__global__ __launch_bounds__(256) void layer_gemm(
    const float* __restrict__ A0, const unsigned short* __restrict__ pre,
    const unsigned short* __restrict__ Wt, const float* __restrict__ bias,
    float* __restrict__ C, int N, int n_pre, int do_relu) {
  __shared__ __align__(16) unsigned short As[FDIM * FDIM];
  __shared__ __align__(16) unsigned short Bs[FDIM * FDIM];
  const int tid = threadIdx.x;
  const int row0 = blockIdx.x * 128;
  const int wave = tid >> 6, lane = tid & 63;
  const int l16 = lane & 15, lq = lane >> 4;
  const int do_init = (A0 != nullptr);

  f32x4 acc[2][8];
#pragma unroll
  for (int m = 0; m < 2; ++m)
#pragma unroll
    for (int n = 0; n < 8; ++n) acc[m][n] = (f32x4){0.f, 0.f, 0.f, 0.f};

  const int n_src = n_pre + do_init;
  for (int s = 0; s < n_src; ++s) {
    __syncthreads();  // previous iter's frag reads done before re-staging
    // stage B = Wt block s ([j][k] bf16), swizzled
    {
      const u16x8* g = (const u16x8*)(Wt + (size_t)s * FDIM * FDIM);
#pragma unroll
      for (int i = 0; i < 8; ++i) {
        int u = tid + 256 * i;
        int r = u >> 4, kb = u & 15;
        ((u16x8*)Bs)[(r << 4) | (kb ^ (r & 7))] = g[u];
      }
    }
    // stage A
    if (do_init && s == 0) {
#pragma unroll
      for (int i = 0; i < 8; ++i) {
        int u = tid + 256 * i;
        int r = u >> 4, kb = u & 15;
        int grow = row0 + r;
        u16x8 v = {0, 0, 0, 0, 0, 0, 0, 0};
        if (grow < N) {
          const float4* rp = (const float4*)(A0 + (size_t)grow * FDIM);
          float4 f0 = rp[kb * 2], f1 = rp[kb * 2 + 1];
          v = (u16x8){f2bf(f0.x), f2bf(f0.y), f2bf(f0.z), f2bf(f0.w),
                      f2bf(f1.x), f2bf(f1.y), f2bf(f1.z), f2bf(f1.w)};
        }
        ((u16x8*)As)[(r << 4) | (kb ^ (r & 7))] = v;
      }
    } else {
      const unsigned short* base = pre + (size_t)(s - do_init) * N * FDIM;
#pragma unroll
      for (int i = 0; i < 8; ++i) {
        int u = tid + 256 * i;
        int r = u >> 4, kb = u & 15;
        int grow = row0 + r;
        u16x8 v = {0, 0, 0, 0, 0, 0, 0, 0};
        if (grow < N) v = ((const u16x8*)(base + (size_t)grow * FDIM))[kb];
        ((u16x8*)As)[(r << 4) | (kb ^ (r & 7))] = v;
      }
    }
    __syncthreads();
    // 4 K-steps of 32
#pragma unroll
    for (int kk = 0; kk < 4; ++kk) {
      bf16x8 a[2], b[8];
#pragma unroll
      for (int m = 0; m < 2; ++m) {
        int r = wave * 32 + m * 16 + l16;
        a[m] = ((const bf16x8*)As)[(r << 4) | ((kk * 4 + lq) ^ (r & 7))];
      }
#pragma unroll
      for (int n = 0; n < 8; ++n) {
        int r = n * 16 + l16;
        b[n] = ((const bf16x8*)Bs)[(r << 4) | ((kk * 4 + lq) ^ (r & 7))];
      }
#pragma unroll
      for (int m = 0; m < 2; ++m)
#pragma unroll
        for (int n = 0; n < 8; ++n)
          acc[m][n] = __builtin_amdgcn_mfma_f32_16x16x32_bf16(a[m], b[n], acc[m][n], 0, 0, 0);
    }
  }

  // epilogue: C/D layout col=lane&15, row=(lane>>4)*4+reg
#pragma unroll
  for (int m = 0; m < 2; ++m) {
    int rbase = row0 + wave * 32 + m * 16 + lq * 4;
#pragma unroll
    for (int n = 0; n < 8; ++n) {
      int col = (n << 4) | l16;
#pragma unroll
      for (int r = 0; r < 4; ++r) {
        int row = rbase + r;
        if (row < N) {
          size_t idx = (size_t)row * FDIM + col;
          float v = acc[m][n][r];
          v += do_init ? bias[col] : C[idx];
          if (do_relu) v = fmaxf(v, 0.f);
          C[idx] = v;
        }
      }
    }
  }
}

// ---------------- host ----------------

extern "C" void kernel_launch(void* const* d_in, const int* in_sizes, int n_in,
                              void* d_out, int out_size, void* d_ws, size_t ws_size,
                              hipStream_t stream) {
  const float* x = (const float*)d_in[0];
  const int* ei = (const int*)d_in[1];
  const int* et = (const int*)d_in[2];
  const float* W[3]    = {(const float*)d_in[3], (const float*)d_in[6], (const float*)d_in[9]};
  const float* root[3] = {(const float*)d_in[4], (const float*)d_in[7], (const float*)d_in[10]};
  const float* bias[3] = {(const float*)d_in[5], (const float*)d_in[8], (const float*)d_in[11]};

  const int N = in_sizes[0] / FDIM;
  const int E = in_sizes[1] / 2;
  const int* src = ei;
  const int* dst = ei + E;
  const int NK = NREL * N;

  char* w = (char*)d_ws;
  size_t pos = 0;
  auto carve = [&](size_t bytes) -> void* {
    pos = (pos + 255) & ~(size_t)255;
    void* p = w + pos;
    pos += bytes;
    return p;
  };
  int* cnt = (int*)carve(sizeof(int) * (NK + 1));
  int* off = (int*)carve(sizeof(int) * (NK + 1));
  int* cur = (int*)carve(sizeof(int) * (NK + 1));
  int* sums = (int*)carve(sizeof(int) * 512);
  int* ss = (int*)carve(sizeof(int) * E);
  unsigned short* Wt = (unsigned short*)carve(sizeof(unsigned short) * 27 * FDIM * FDIM);
  float* h1 = (float*)carve(sizeof(float) * (size_t)N * FDIM);
  float* h2 = (float*)carve(sizeof(float) * (size_t)N * FDIM);
  size_t fixed = (pos + 255) & ~(size_t)255;
  int G = NREL;
  while (G > 1 && fixed + sizeof(unsigned short) * (size_t)G * N * FDIM > ws_size) G >>= 1;
  unsigned short* pre = (unsigned short*)carve(sizeof(unsigned short) * (size_t)G * N * FDIM);

  // ---- one-time edge prep: counting sort by key = rel*N + dst ----
  zero_u32<<<1024, 256, 0, stream>>>((unsigned int*)cnt, NK + 1);
  hist_k<<<(E + 255) / 256, 256, 0, stream>>>(dst, et, E, cnt, N);
  const int n_scan = NK + 1;
  const int nchunk = (n_scan + SCHUNK - 1) / SCHUNK;  // 196 for N=100k (<256)
  scan_partial<<<nchunk, 256, 0, stream>>>(cnt, n_scan, sums);
  scan_sums<<<1, 256, 0, stream>>>(sums, nchunk);
  scan_final<<<nchunk, 256, 0, stream>>>(cnt, n_scan, sums, off);
  hipMemcpyAsync(cur, off, sizeof(int) * NK, hipMemcpyDeviceToDevice, stream);
  sort_k<<<(E + 255) / 256, 256, 0, stream>>>(src, dst, et, E, cur, ss, N);
  wtrans_k<<<27, 256, 0, stream>>>(root[0], W[0], root[1], W[1], root[2], W[2], Wt);

  // ---- 3 layers ----
  const float* in_p = x;
  float* outs[3] = {h1, h2, (float*)d_out};
  const int npass = NREL / G;
  for (int L = 0; L < 3; ++L) {
    unsigned short* WtL = Wt + (size_t)L * 9 * FDIM * FDIM;
    for (int p = 0; p < npass; ++p) {
      seg_mean_k<<<(G * N) / 8, 256, 0, stream>>>(in_p, ss, off, p * G * N, G * N, pre);
      const unsigned short* Wpass = WtL + (size_t)(p == 0 ? 0 : 1 + p * G) * FDIM * FDIM;
      layer_gemm<<<(N + 127) / 128, 256, 0, stream>>>(
          p == 0 ? in_p : nullptr, pre, Wpass, bias[L], outs[L], N, G,
          (p == npass - 1) ? 1 : 0);
    }
    in_p = outs[L];
  }
}